// Round 2
// baseline (4515.618 us; speedup 1.0000x reference)
//
#include <hip/hip_runtime.h>
#include <math.h>

// ---------------- problem constants ----------------
#define Lsz   1024
#define Tsz   32
#define Bsz   64
#define DIN   300
#define REG   36
#define Rsz   128
#define R3sz  384
#define H3sz  3072
#define GENROWS 49152   // R3sz * Rsz

__device__ __forceinline__ float sigf(float x) { return 1.f / (1.f + __expf(-x)); }

// =====================================================================
// Generic tiled SGEMM (64x64 tile, 4x4 reg tile). z-dim selects a second
// problem (W2/bias2/C2) sharing the same A — used to fuse q/k projections.
// mode 0: C row-major. mode 1: scatter to [t][n][b] for m = b*32+t.
// =====================================================================
__global__ __launch_bounds__(256) void gemm_bias(
    const float* __restrict__ A, int lda,
    const float* __restrict__ W1, const float* __restrict__ W2, int ldw, int woff,
    const float* __restrict__ bias1, const float* __restrict__ bias2,
    float* __restrict__ C1, float* __restrict__ C2,
    int M, int N, int K, int mode)
{
    const float* W = blockIdx.z ? W2 : W1;
    const float* bias = blockIdx.z ? bias2 : bias1;
    float* C = blockIdx.z ? C2 : C1;
    __shared__ float As[16][68];
    __shared__ float Ws[16][68];
    int tid = threadIdx.x;
    int tx = tid & 15, ty = tid >> 4;
    int m0 = blockIdx.y * 64, n0 = blockIdx.x * 64;
    float acc[4][4];
#pragma unroll
    for (int i = 0; i < 4; i++)
#pragma unroll
        for (int j = 0; j < 4; j++) acc[i][j] = 0.f;

    for (int k0 = 0; k0 < K; k0 += 16) {
#pragma unroll
        for (int l = 0; l < 4; l++) {
            int e = l * 256 + tid;
            int kk = e & 15, mm = e >> 4;
            int m = m0 + mm, k = k0 + kk;
            As[kk][mm] = (m < M && k < K) ? A[(size_t)m * lda + k] : 0.f;
        }
#pragma unroll
        for (int l = 0; l < 4; l++) {
            int e = l * 256 + tid;
            int kk = e & 15, nn = e >> 4;
            int n = n0 + nn, k = k0 + kk;
            Ws[kk][nn] = (n < N && k < K) ? W[(size_t)n * ldw + woff + k] : 0.f;
        }
        __syncthreads();
#pragma unroll
        for (int kk = 0; kk < 16; kk++) {
            float4 a4 = *(const float4*)&As[kk][ty * 4];
            float4 w4 = *(const float4*)&Ws[kk][tx * 4];
            float av[4] = {a4.x, a4.y, a4.z, a4.w};
            float wv[4] = {w4.x, w4.y, w4.z, w4.w};
#pragma unroll
            for (int i = 0; i < 4; i++)
#pragma unroll
                for (int j = 0; j < 4; j++) acc[i][j] = fmaf(av[i], wv[j], acc[i][j]);
        }
        __syncthreads();
    }
#pragma unroll
    for (int i = 0; i < 4; i++) {
        int m = m0 + ty * 4 + i;
        if (m >= M) continue;
#pragma unroll
        for (int j = 0; j < 4; j++) {
            int n = n0 + tx * 4 + j;
            if (n >= N) continue;
            float val = acc[i][j] + (bias ? bias[n] : 0.f);
            if (mode == 0) C[(size_t)m * N + n] = val;
            else           C[((size_t)(m & 31) * N + n) * 64 + (m >> 5)] = val;
        }
    }
}

// =====================================================================
// Big-tile SGEMM: 128x128 tile, 8x8 register tile, K-chunk 16.
// Same contract as gemm_bias (single problem).
// =====================================================================
__global__ __launch_bounds__(256) void gemm128(
    const float* __restrict__ A, int lda,
    const float* __restrict__ W, int ldw, int woff,
    const float* __restrict__ bias,
    float* __restrict__ C, int M, int N, int K, int mode)
{
    __shared__ float As[16][136];
    __shared__ float Ws[16][136];
    int tid = threadIdx.x;
    int tx = tid & 15, ty = tid >> 4;
    int m0 = blockIdx.y * 128, n0 = blockIdx.x * 128;
    float acc[8][8];
#pragma unroll
    for (int i = 0; i < 8; i++)
#pragma unroll
        for (int j = 0; j < 8; j++) acc[i][j] = 0.f;

    for (int k0 = 0; k0 < K; k0 += 16) {
#pragma unroll
        for (int l = 0; l < 8; l++) {
            int e = l * 256 + tid;
            int kk = e & 15, mm = e >> 4;
            int m = m0 + mm, k = k0 + kk;
            As[kk][mm] = (m < M && k < K) ? A[(size_t)m * lda + k] : 0.f;
        }
#pragma unroll
        for (int l = 0; l < 8; l++) {
            int e = l * 256 + tid;
            int kk = e & 15, nn = e >> 4;
            int n = n0 + nn, k = k0 + kk;
            Ws[kk][nn] = (n < N && k < K) ? W[(size_t)n * ldw + woff + k] : 0.f;
        }
        __syncthreads();
#pragma unroll
        for (int kk = 0; kk < 16; kk++) {
            float a[8], b[8];
            *(float4*)&a[0] = *(const float4*)&As[kk][ty * 8];
            *(float4*)&a[4] = *(const float4*)&As[kk][ty * 8 + 4];
            *(float4*)&b[0] = *(const float4*)&Ws[kk][tx * 8];
            *(float4*)&b[4] = *(const float4*)&Ws[kk][tx * 8 + 4];
#pragma unroll
            for (int i = 0; i < 8; i++)
#pragma unroll
                for (int j = 0; j < 8; j++) acc[i][j] = fmaf(a[i], b[j], acc[i][j]);
        }
        __syncthreads();
    }
#pragma unroll
    for (int i = 0; i < 8; i++) {
        int m = m0 + ty * 8 + i;
        if (m >= M) continue;
#pragma unroll
        for (int j = 0; j < 8; j++) {
            int n = n0 + tx * 8 + j;
            if (n >= N) continue;
            float val = acc[i][j] + (bias ? bias[n] : 0.f);
            if (mode == 0) C[(size_t)m * N + n] = val;
            else           C[((size_t)(m & 31) * N + n) * 64 + (m >> 5)] = val;
        }
    }
}

// =====================================================================
// Generated weights: out[i][rk] = dot(genW[rk][:], base[i][:]) + bias[rk].
// Lane = rk (coalesced stores); base reads are wave-uniform -> s_load, so
// the inner loop is pure v_fma(v, s, v). grid (194, 2):
//   blocks 0..191: z=0 -> gen_Wih->WihAll, z=1 -> gen_Whh->WhhAll (49152 rows)
//   blocks 192..193: z=0 -> gen_Wbih->bihAll, z=1 -> gen_Wbhh->bbhh (384 rows)
// =====================================================================
__global__ __launch_bounds__(256) void genw_kernel(
    const float* __restrict__ gen_Wih, const float* __restrict__ gen_bih,
    const float* __restrict__ gen_Whh, const float* __restrict__ gen_bhh,
    const float* __restrict__ gen_Wbih, const float* __restrict__ gen_bbih,
    const float* __restrict__ gen_Wbhh, const float* __restrict__ gen_bbhh,
    const float* __restrict__ base,
    float* __restrict__ WihAll, float* __restrict__ WhhAll,
    float* __restrict__ bihAll, float* __restrict__ bhhAll)
{
    int z = blockIdx.y;
    const float* W; const float* bi; float* out; int nr; int rk;
    if (blockIdx.x < 192) {
        rk = blockIdx.x * 256 + threadIdx.x;
        W = z ? gen_Whh : gen_Wih;  bi = z ? gen_bhh : gen_bih;
        out = z ? WhhAll : WihAll;  nr = GENROWS;
    } else {
        rk = (blockIdx.x - 192) * 256 + threadIdx.x;
        if (rk >= R3sz) return;
        W = z ? gen_Wbhh : gen_Wbih; bi = z ? gen_bbhh : gen_bbih;
        out = z ? bhhAll : bihAll;   nr = R3sz;
    }
    const float* wrow = W + (size_t)rk * Rsz;
    float acc[64];
#pragma unroll
    for (int i = 0; i < 64; i++) acc[i] = 0.f;
    for (int pc = 0; pc < Rsz; pc += 16) {
        float w[16];
        *(float4*)&w[0]  = *(const float4*)&wrow[pc];
        *(float4*)&w[4]  = *(const float4*)&wrow[pc + 4];
        *(float4*)&w[8]  = *(const float4*)&wrow[pc + 8];
        *(float4*)&w[12] = *(const float4*)&wrow[pc + 12];
#pragma unroll
        for (int i = 0; i < 64; i++) {
            const float4* bp = (const float4*)(base + (size_t)i * Rsz + pc); // uniform -> s_load
            float4 b0 = bp[0], b1 = bp[1], b2 = bp[2], b3 = bp[3];
            float s = acc[i];
            s = fmaf(w[0], b0.x, s);  s = fmaf(w[1], b0.y, s);
            s = fmaf(w[2], b0.z, s);  s = fmaf(w[3], b0.w, s);
            s = fmaf(w[4], b1.x, s);  s = fmaf(w[5], b1.y, s);
            s = fmaf(w[6], b1.z, s);  s = fmaf(w[7], b1.w, s);
            s = fmaf(w[8], b2.x, s);  s = fmaf(w[9], b2.y, s);
            s = fmaf(w[10], b2.z, s); s = fmaf(w[11], b2.w, s);
            s = fmaf(w[12], b3.x, s); s = fmaf(w[13], b3.y, s);
            s = fmaf(w[14], b3.z, s); s = fmaf(w[15], b3.w, s);
            acc[i] = s;
        }
    }
    float bv = bi[rk];
#pragma unroll
    for (int i = 0; i < 64; i++)
        out[(size_t)i * nr + rk] = acc[i] + bv;
}

// =====================================================================
// Fused image-side precompute: per image i -> img_glob row (in LDS),
// iv = l2norm(row), base[i] = W_reduce_img @ row + b. grid 64.
// =====================================================================
__global__ __launch_bounds__(256) void img_kernel(
    const float* __restrict__ img_embed, const float* __restrict__ W_reduce_img,
    const float* __restrict__ b_reduce_img,
    float* __restrict__ base, float* __restrict__ iv)
{
    int i = blockIdx.x;
    int tid = threadIdx.x;
    __shared__ float row[Lsz];
    __shared__ float ps[4];
    for (int c = tid; c < Lsz; c += 256) {
        float s = 0.f;
        for (int r = 0; r < REG; r++) s += img_embed[((size_t)i * REG + r) * Lsz + c];
        row[c] = s * (1.f / (float)REG);
    }
    __syncthreads();
    float ss = 0.f;
    for (int c = tid; c < Lsz; c += 256) { float x = row[c]; ss = fmaf(x, x, ss); }
#pragma unroll
    for (int off = 32; off; off >>= 1) ss += __shfl_down(ss, off, 64);
    int lane = tid & 63, w = tid >> 6;
    if (lane == 0) ps[w] = ss;
    __syncthreads();
    float inv = 1.f / (sqrtf(ps[0] + ps[1] + ps[2] + ps[3]) + 1e-8f);
    for (int c = tid; c < Lsz; c += 256)
        iv[(size_t)i * Lsz + c] = row[c] * inv;
    // base row: wave w handles o = w*32 .. w*32+31, lanes split K
    for (int o = w * 32; o < w * 32 + 32; o++) {
        float a = 0.f;
        const float* wr = W_reduce_img + (size_t)o * Lsz + lane * 16;
        const float* rr = row + lane * 16;
#pragma unroll
        for (int u = 0; u < 16; u++) a = fmaf(wr[u], rr[u], a);
#pragma unroll
        for (int off = 32; off; off >>= 1) a += __shfl_down(a, off, 64);
        if (lane == 0) base[(size_t)i * Rsz + o] = a + b_reduce_img[o];
    }
}

// =====================================================================
// Fused recurrence step: flat grid of 2560 blocks.
//   blocks 0..511   : bidirectional caption GRU (dir = bid>>8)
//   blocks 512..2559: generated-weight GRU (i = (bid-512)>>5)
// =====================================================================
__global__ __launch_bounds__(256) void recur_step(
    const float* __restrict__ giT_f, const float* __restrict__ giT_b,
    float* __restrict__ hfT, float* __restrict__ hbT,
    const float* __restrict__ Whh_f, const float* __restrict__ Whh_b,
    const float* __restrict__ bhh_f, const float* __restrict__ bhh_b,
    const float* __restrict__ capT, const float* __restrict__ WihAll,
    const float* __restrict__ WhhAll, const float* __restrict__ bihAll,
    const float* __restrict__ bhhAll, const float* __restrict__ hprevT,
    float* __restrict__ hcurT, float* __restrict__ hmaxT, int step)
{
    int bid = blockIdx.x;
    int b = threadIdx.x & 63;
    if (bid < 512) {
        // ---- caption bi-GRU ----
        const int H = Lsz, B = Bsz;
        int dir = bid >> 8;
        const float* giT = dir ? giT_b : giT_f;
        float* hT        = dir ? hbT   : hfT;
        const float* Whh = dir ? Whh_b : Whh_f;
        const float* bhh = dir ? bhh_b : bhh_f;
        int t = dir ? (Tsz - 1 - step) : step;
        const float* hprev = nullptr;
        if (step > 0) hprev = hT + (size_t)(dir ? (t + 1) : (t - 1)) * H * B;
        int j = (bid & 255) * 4 + (threadIdx.x >> 6);
        j = __builtin_amdgcn_readfirstlane(j);
        const float* Wr = Whh + (size_t)j * H;
        const float* Wz = Whh + (size_t)(H + j) * H;
        const float* Wn = Whh + (size_t)(2 * H + j) * H;
        float ar = 0.f, az = 0.f, an = 0.f;
        if (hprev) {
            for (int k = 0; k < H; k += 4) {
#pragma unroll
                for (int u = 0; u < 4; u++) {
                    float hv = hprev[(size_t)(k + u) * B + b];
                    ar = fmaf(hv, Wr[k + u], ar);
                    az = fmaf(hv, Wz[k + u], az);
                    an = fmaf(hv, Wn[k + u], an);
                }
            }
        }
        size_t gbase = (size_t)t * H3sz * B + b;
        float gr = giT[gbase + (size_t)j * B];
        float gz = giT[gbase + (size_t)(H + j) * B];
        float gn = giT[gbase + (size_t)(2 * H + j) * B];
        float r = sigf(gr + ar + bhh[j]);
        float z = sigf(gz + az + bhh[H + j]);
        float n = tanhf(gn + r * (an + bhh[2 * H + j]));
        float hp = hprev ? hprev[(size_t)j * B + b] : 0.f;
        hT[(size_t)t * H * B + (size_t)j * B + b] = (1.f - z) * n + z * hp;
    } else {
        // ---- generated-weight GRU ----
        const int R = Rsz, B = Bsz;
        int g = bid - 512;
        int i = g >> 5;
        int j = (g & 31) * 4 + (threadIdx.x >> 6);
        j = __builtin_amdgcn_readfirstlane(j);
        const float* Wih = WihAll + (size_t)i * GENROWS;
        const float* Whh = WhhAll + (size_t)i * GENROWS;
        const float* cap = capT + (size_t)step * R * B;
        const float* hp = (step > 0) ? hprevT + (size_t)i * R * B : nullptr;
        const float* Wir = Wih + (size_t)j * R;
        const float* Wiz = Wih + (size_t)(R + j) * R;
        const float* Win = Wih + (size_t)(2 * R + j) * R;
        const float* Whr = Whh + (size_t)j * R;
        const float* Whz = Whh + (size_t)(R + j) * R;
        const float* Whn = Whh + (size_t)(2 * R + j) * R;
        float air = 0, aiz = 0, ain = 0, ahr = 0, ahz = 0, ahn = 0;
#pragma unroll 8
        for (int k = 0; k < R; k++) {
            float cv = cap[k * B + b];
            air = fmaf(cv, Wir[k], air);
            aiz = fmaf(cv, Wiz[k], aiz);
            ain = fmaf(cv, Win[k], ain);
        }
        if (hp) {
#pragma unroll 8
            for (int k = 0; k < R; k++) {
                float hv = hp[k * B + b];
                ahr = fmaf(hv, Whr[k], ahr);
                ahz = fmaf(hv, Whz[k], ahz);
                ahn = fmaf(hv, Whn[k], ahn);
            }
        }
        const float* bih = bihAll + (size_t)i * R3sz;
        const float* bhh = bhhAll + (size_t)i * R3sz;
        float r = sigf(air + bih[j] + ahr + bhh[j]);
        float z = sigf(aiz + bih[R + j] + ahz + bhh[R + j]);
        float n = tanhf(ain + bih[2 * R + j] + r * (ahn + bhh[2 * R + j]));
        float hpv = hp ? hp[(size_t)j * B + b] : 0.f;
        float h = (1.f - z) * n + z * hpv;
        size_t idx = ((size_t)i * R + j) * B + b;
        hcurT[idx] = h;
        hmaxT[idx] = (step == 0) ? h : fmaxf(hmaxT[idx], h);
    }
}

// =====================================================================
// txt = (hf+hb)/2, [t][c][b] -> [b][t][c] transpose. grid (32, 16).
// =====================================================================
__global__ __launch_bounds__(256) void txt_combine(
    const float* __restrict__ hfT, const float* __restrict__ hbT,
    float* __restrict__ txt)
{
    __shared__ float s[64][65];
    int t = blockIdx.x;
    int c0 = blockIdx.y * 64;
    int tid = threadIdx.x;
#pragma unroll
    for (int l = 0; l < 16; l++) {
        int e = l * 256 + tid;
        int cc = e >> 6, b = e & 63;
        size_t idx = ((size_t)t * Lsz + c0 + cc) * Bsz + b;
        s[cc][b] = 0.5f * (hfT[idx] + hbT[idx]);
    }
    __syncthreads();
#pragma unroll
    for (int l = 0; l < 16; l++) {
        int e = l * 256 + tid;
        int b = e >> 6, cc = e & 63;
        txt[((size_t)b * Tsz + t) * Lsz + c0 + cc] = s[cc][b];
    }
}

// =====================================================================
// Self-attention: logits -> softmax -> apply + residual. grid (64, 8).
// =====================================================================
__global__ __launch_bounds__(256) void attn_kernel(
    const float* __restrict__ q, const float* __restrict__ kmat,
    const float* __restrict__ v, const float* __restrict__ txt,
    const float* __restrict__ gamma_p, float* __restrict__ xattn)
{
    __shared__ float qs[32][129];
    __shared__ float ks[32][129];
    __shared__ float As[32][33];
    int b = blockIdx.x;
    int c0 = blockIdx.y * 128;
    int tid = threadIdx.x;
    for (int e = tid; e < Tsz * Rsz; e += 256) {
        qs[e >> 7][e & 127] = q[(size_t)b * Tsz * Rsz + e];
        ks[e >> 7][e & 127] = kmat[(size_t)b * Tsz * Rsz + e];
    }
    __syncthreads();
    for (int e = tid; e < Tsz * Tsz; e += 256) {
        int t = e >> 5, ss = e & 31;
        float acc = 0.f;
#pragma unroll 4
        for (int o = 0; o < Rsz; o++) acc = fmaf(qs[t][o], ks[ss][o], acc);
        As[t][ss] = acc;
    }
    __syncthreads();
    if (tid < 32) {
        int t = tid;
        float mx = -1e30f;
#pragma unroll
        for (int ss = 0; ss < 32; ss++) mx = fmaxf(mx, As[t][ss]);
        float sum = 0.f;
        float ex[32];
#pragma unroll
        for (int ss = 0; ss < 32; ss++) { ex[ss] = __expf(As[t][ss] - mx); sum += ex[ss]; }
        float inv = 1.f / sum;
#pragma unroll
        for (int ss = 0; ss < 32; ss++) As[t][ss] = ex[ss] * inv;
    }
    __syncthreads();
    float gamma = *gamma_p;
    for (int e = tid; e < Tsz * 128; e += 256) {
        int tt = e >> 7, c = c0 + (e & 127);
        float acc = 0.f;
#pragma unroll 8
        for (int ss = 0; ss < Tsz; ss++)
            acc = fmaf(As[tt][ss], v[((size_t)b * Tsz + ss) * Lsz + c], acc);
        size_t oidx = ((size_t)b * Tsz + tt) * Lsz + c;
        xattn[oidx] = gamma * acc + txt[oidx];
    }
}

// ---------------- length-masked mean pool, grid (64,4) ----------------
__global__ __launch_bounds__(256) void pool_kernel(
    const float* __restrict__ xattn, const int* __restrict__ lens,
    float* __restrict__ txt_embed)
{
    int b = blockIdx.x;
    int c = blockIdx.y * 256 + threadIdx.x;
    int len = lens[b];
    float s = 0.f;
    for (int t = 0; t < len; t++) s += xattn[((size_t)b * Tsz + t) * Lsz + c];
    txt_embed[(size_t)b * Lsz + c] = s / (float)len;
}

// =====================================================================
// base_fc[b][n] = dot(txt_emb[b][:], W_txt_fc[n][0:1024])  (no bias here;
// bias folded into sims). grid 256, wave = one n, lanes split K.
// =====================================================================
__global__ __launch_bounds__(256) void basefc_kernel(
    const float* __restrict__ temb, const float* __restrict__ W,
    float* __restrict__ out)
{
    int lane = threadIdx.x & 63, w = threadIdx.x >> 6;
    int n = blockIdx.x * 4 + w;
    const float* wr = W + (size_t)n * (Rsz + Lsz) + lane * 16;
    float wv[16];
#pragma unroll
    for (int u = 0; u < 4; u++) *(float4*)&wv[u * 4] = *(const float4*)&wr[u * 4];
    for (int b = 0; b < Bsz; b++) {
        const float* te = temb + (size_t)b * Lsz + lane * 16;
        float tv[16];
#pragma unroll
        for (int u = 0; u < 4; u++) *(float4*)&tv[u * 4] = *(const float4*)&te[u * 4];
        float a = 0.f;
#pragma unroll
        for (int u = 0; u < 16; u++) a = fmaf(wv[u], tv[u], a);
#pragma unroll
        for (int off = 32; off; off >>= 1) a += __shfl_down(a, off, 64);
        if (lane == 0) out[(size_t)b * Lsz + n] = a;
    }
}

// ---------------- hmax [i][j][b] -> [(i*64+b)][j], grid 64 ----------------
__global__ __launch_bounds__(256) void hmax_transpose(
    const float* __restrict__ hmaxT, float* __restrict__ hstd)
{
    __shared__ float s[128][65];
    int i = blockIdx.x, tid = threadIdx.x;
#pragma unroll
    for (int l = 0; l < 32; l++) {
        int e = l * 256 + tid;
        int j = e >> 6, b = e & 63;
        s[j][b] = hmaxT[((size_t)i * Rsz + j) * Bsz + b];
    }
    __syncthreads();
#pragma unroll
    for (int l = 0; l < 32; l++) {
        int e = l * 256 + tid;
        int b = e >> 7, j = e & 127;
        hstd[((size_t)i * Bsz + b) * Rsz + j] = s[j][b];
    }
}

// ---------------- final fused l2norm + cosine, grid 4096 ----------------
__global__ __launch_bounds__(256) void sims_kernel(
    const float* __restrict__ fc_delta, const float* __restrict__ base_fc,
    const float* __restrict__ bfc, const float* __restrict__ iv,
    float* __restrict__ out)
{
    int m = blockIdx.x;          // i*64 + b
    int i = m >> 6, b = m & 63;
    int tid = threadIdx.x;
    float s1 = 0.f, s2 = 0.f;
    for (int c = tid; c < Lsz; c += 256) {
        float f = fc_delta[(size_t)m * Lsz + c] + base_fc[(size_t)b * Lsz + c] + bfc[c];
        s1 = fmaf(f, f, s1);
        s2 = fmaf(f, iv[(size_t)i * Lsz + c], s2);
    }
#pragma unroll
    for (int off = 32; off; off >>= 1) {
        s1 += __shfl_down(s1, off, 64);
        s2 += __shfl_down(s2, off, 64);
    }
    __shared__ float p1[4], p2[4];
    int w = tid >> 6;
    if ((tid & 63) == 0) { p1[w] = s1; p2[w] = s2; }
    __syncthreads();
    if (tid == 0) {
        float t1 = p1[0] + p1[1] + p1[2] + p1[3];
        float t2 = p2[0] + p2[1] + p2[2] + p2[3];
        out[m] = t2 / (sqrtf(t1) + 1e-8f);
    }
}

// =====================================================================
extern "C" void kernel_launch(void* const* d_in, const int* in_sizes, int n_in,
                              void* d_out, int out_size, void* d_ws, size_t ws_size,
                              hipStream_t stream)
{
    const float* img_embed    = (const float*)d_in[0];
    const float* cap_embed    = (const float*)d_in[1];
    const int*   lens         = (const int*)d_in[2];
    const float* W_reduce_img = (const float*)d_in[3];
    const float* b_reduce_img = (const float*)d_in[4];
    const float* W_reduce_txt = (const float*)d_in[5];
    const float* b_reduce_txt = (const float*)d_in[6];
    const float* gru_Wih_f    = (const float*)d_in[7];
    const float* gru_Whh_f    = (const float*)d_in[8];
    const float* gru_bih_f    = (const float*)d_in[9];
    const float* gru_bhh_f    = (const float*)d_in[10];
    const float* gru_Wih_b    = (const float*)d_in[11];
    const float* gru_Whh_b    = (const float*)d_in[12];
    const float* gru_bih_b    = (const float*)d_in[13];
    const float* gru_bhh_b    = (const float*)d_in[14];
    const float* sa_Wq        = (const float*)d_in[15];
    const float* sa_bq        = (const float*)d_in[16];
    const float* sa_Wk        = (const float*)d_in[17];
    const float* sa_bk        = (const float*)d_in[18];
    const float* sa_Wv        = (const float*)d_in[19];
    const float* sa_bv        = (const float*)d_in[20];
    const float* sa_gamma     = (const float*)d_in[21];
    const float* gen_Wih      = (const float*)d_in[22];
    const float* gen_bih      = (const float*)d_in[23];
    const float* gen_Whh      = (const float*)d_in[24];
    const float* gen_bhh      = (const float*)d_in[25];
    const float* gen_Wbih     = (const float*)d_in[26];
    const float* gen_bbih     = (const float*)d_in[27];
    const float* gen_Wbhh     = (const float*)d_in[28];
    const float* gen_bbhh     = (const float*)d_in[29];
    const float* W_txt_fc     = (const float*)d_in[30];
    const float* b_txt_fc     = (const float*)d_in[31];

    float* ws = (float*)d_ws;
    size_t off = 0;
    auto alloc = [&](size_t n) { float* p = ws + off; off += n; return p; };
    float* giT_f    = alloc((size_t)Tsz * H3sz * Bsz);
    float* giT_b    = alloc((size_t)Tsz * H3sz * Bsz);
    float* hfT      = alloc((size_t)Tsz * Lsz * Bsz);
    float* hbT      = alloc((size_t)Tsz * Lsz * Bsz);
    float* capT     = alloc((size_t)Tsz * Rsz * Bsz);
    float* txt      = alloc((size_t)Bsz * Tsz * Lsz);
    float* qbuf     = alloc((size_t)Bsz * Tsz * Rsz);
    float* kbuf     = alloc((size_t)Bsz * Tsz * Rsz);
    float* vbuf     = alloc((size_t)Bsz * Tsz * Lsz);
    float* xattn    = alloc((size_t)Bsz * Tsz * Lsz);
    float* txt_emb  = alloc((size_t)Bsz * Lsz);
    float* base     = alloc((size_t)Bsz * Rsz);
    float* iv       = alloc((size_t)Bsz * Lsz);
    float* WihAll   = alloc((size_t)Bsz * GENROWS);
    float* WhhAll   = alloc((size_t)Bsz * GENROWS);
    float* bihAll   = alloc((size_t)Bsz * R3sz);
    float* bhhAll   = alloc((size_t)Bsz * R3sz);
    float* hA       = alloc((size_t)Bsz * Rsz * Bsz);
    float* hB       = alloc((size_t)Bsz * Rsz * Bsz);
    float* hmaxT    = alloc((size_t)Bsz * Rsz * Bsz);
    float* hstd     = alloc((size_t)Bsz * Bsz * Rsz);
    float* base_fc  = alloc((size_t)Bsz * Lsz);
    float* fc_delta = alloc((size_t)Bsz * Bsz * Lsz);

    // 1) image-side: img_glob/base/iv fused, then generated weights
    img_kernel<<<64, 256, 0, stream>>>(img_embed, W_reduce_img, b_reduce_img, base, iv);
    genw_kernel<<<dim3(194, 2), 256, 0, stream>>>(gen_Wih, gen_bih, gen_Whh, gen_bhh,
        gen_Wbih, gen_bbih, gen_Wbhh, gen_bbhh, base, WihAll, WhhAll, bihAll, bhhAll);

    // 2) caption-side input gates + reduced captions
    gemm128<<<dim3(24, 16), 256, 0, stream>>>(cap_embed, DIN, gru_Wih_f, DIN, 0,
        gru_bih_f, giT_f, Bsz * Tsz, H3sz, DIN, 1);
    gemm128<<<dim3(24, 16), 256, 0, stream>>>(cap_embed, DIN, gru_Wih_b, DIN, 0,
        gru_bih_b, giT_b, Bsz * Tsz, H3sz, DIN, 1);
    gemm_bias<<<dim3(2, 32), 256, 0, stream>>>(cap_embed, DIN, W_reduce_txt, W_reduce_txt,
        DIN, 0, b_reduce_txt, b_reduce_txt, capT, capT, Bsz * Tsz, Rsz, DIN, 1);

    // 3) both recurrences fused, one launch per step
    for (int s = 0; s < Tsz; s++) {
        const float* hp = (s == 0) ? hA : ((s & 1) ? hA : hB);
        float* hc = (s & 1) ? hB : hA;
        recur_step<<<2560, 256, 0, stream>>>(giT_f, giT_b, hfT, hbT,
            gru_Whh_f, gru_Whh_b, gru_bhh_f, gru_bhh_b,
            capT, WihAll, WhhAll, bihAll, bhhAll, hp, hc, hmaxT, s);
    }
    hmax_transpose<<<64, 256, 0, stream>>>(hmaxT, hstd);

    // 4) combine + self-attention
    txt_combine<<<dim3(32, 16), 256, 0, stream>>>(hfT, hbT, txt);
    gemm_bias<<<dim3(2, 32, 2), 256, 0, stream>>>(txt, Lsz, sa_Wq, sa_Wk, Lsz, 0,
        sa_bq, sa_bk, qbuf, kbuf, Bsz * Tsz, Rsz, Lsz, 0);
    gemm128<<<dim3(8, 16), 256, 0, stream>>>(txt, Lsz, sa_Wv, Lsz, 0, sa_bv,
        vbuf, Bsz * Tsz, Lsz, Lsz, 0);
    attn_kernel<<<dim3(64, 8), 256, 0, stream>>>(qbuf, kbuf, vbuf, txt, sa_gamma, xattn);

    // 5) pool + image-independent FC part
    pool_kernel<<<dim3(64, 4), 256, 0, stream>>>(xattn, lens, txt_emb);
    basefc_kernel<<<256, 256, 0, stream>>>(txt_emb, W_txt_fc, base_fc);

    // 6) per-(image,caption) FC delta + fused norm/cosine
    gemm128<<<dim3(8, 32), 256, 0, stream>>>(hstd, Rsz, W_txt_fc, Rsz + Lsz, Lsz,
        nullptr, fc_delta, Bsz * Bsz, Lsz, Rsz, 0);
    sims_kernel<<<4096, 256, 0, stream>>>(fc_delta, base_fc, b_txt_fc, iv, (float*)d_out);
}